// Round 15
// baseline (153.831 us; speedup 1.0000x reference)
//
#include <hip/hip_runtime.h>

typedef unsigned short u16;
typedef __attribute__((ext_vector_type(4))) float f32x4;
typedef __attribute__((ext_vector_type(8))) short bf16x8;
typedef __attribute__((ext_vector_type(4))) u16 u16x4;
typedef __attribute__((ext_vector_type(8))) u16 u16x8;

__device__ __forceinline__ u16 f2bf(float f) {
    unsigned u = __float_as_uint(f);
    unsigned r = (u + 0x7FFFu + ((u >> 16) & 1u)) >> 16;
    return (u16)r;
}

__device__ __forceinline__ void gld16(const void* g, void* l) {
    __builtin_amdgcn_global_load_lds(
        (const __attribute__((address_space(1))) unsigned*)g,
        (__attribute__((address_space(3))) unsigned*)l,
        16, 0, 0);
}

// XCD-aware bijective block remap (T1). Verified R11: scores FETCH 74.7->27.7MB.
__device__ __forceinline__ void xcd_map(int& bx, int& by, int& bz) {
    const int gx = gridDim.x, gxy = gridDim.x * gridDim.y;
    const int F = blockIdx.x + gx * (blockIdx.y + gridDim.y * blockIdx.z);
    const int cpx = (gxy * gridDim.z) >> 3;
    const int L = (F & 7) * cpx + (F >> 3);
    bz = L / gxy;
    const int r = L % gxy;
    by = r / gx;
    bx = r % gx;
}

// ---------------- fused prologue: all casts + den zero, ONE launch ----------------
__global__ __launch_bounds__(256) void prep_kernel(
    const float* __restrict__ x, const float* __restrict__ Wq,
    const float* __restrict__ Wk, const float* __restrict__ Wv,
    u16* __restrict__ xb, u16* __restrict__ wqk, u16* __restrict__ wvb,
    float* __restrict__ den) {
    const int NX = 2097152, NW = 262144;
    const int total = NX + 3 * NW + 2048;
    int i = blockIdx.x * blockDim.x + threadIdx.x;
    int stride = gridDim.x * blockDim.x;
    for (; i < total; i += stride) {
        const float* src; u16* dst; int j;
        if (i < NX)               { src = x;  dst = xb;            j = i; }
        else if (i < NX + NW)     { src = Wq; dst = wqk;           j = i - NX; }
        else if (i < NX + 2 * NW) { src = Wk; dst = wqk + 1048576; j = i - NX - NW; }
        else if (i < NX + 3 * NW) { src = Wv; dst = wvb;           j = i - NX - 2 * NW; }
        else { ((f32x4*)den)[i - NX - 3 * NW] = f32x4{0.f, 0.f, 0.f, 0.f}; continue; }
        f32x4 v = ((const f32x4*)src)[j];
        u16x4 o;
        o[0] = f2bf(v[0]); o[1] = f2bf(v[1]); o[2] = f2bf(v[2]); o[3] = f2bf(v[3]);
        ((u16x4*)dst)[j] = o;
    }
}

// ======== 256x256 single-barrier-per-phase bf16 GEMM body (R7-proven) ========
// EPI 0: C = bf16(acc*scale). EPI 2: P_unnorm = bf16(exp(acc*scale)) + denom.
template <int EPI>
__device__ __forceinline__ void g256_body(
    int bx, int by, int bz, char* smem,
    const u16* __restrict__ A, const u16* __restrict__ Bm, void* __restrict__ Cv,
    int K, int lda, int ldb, int ldc,
    long long sA, long long sB, long long sC, float scale,
    float* __restrict__ denom) {
    const u16* Ab = A + (long long)bz * sA;
    const u16* Bb = Bm + (long long)bz * sB;

    const int tid  = threadIdx.x;
    const int lane = tid & 63;
    const int w    = tid >> 6;
    const int wm   = w >> 2;   // 0..1
    const int wn   = w & 3;    // 0..3
    const int rowBase = bx << 8;
    const int colBase = by << 8;
    const int NT = K >> 6;     // requires NT >= 2
    const int aRow = lane & 15;

    auto stage = [&](int tile, int h) {
        if (tile >= NT) return;
        const int db = tile & 1;
        const int kt = tile << 6;
        const u16* mat; int ldm, rb, halfRow; char* region;
        if (h == 0)      { mat = Ab; ldm = lda; rb = rowBase; halfRow = 0;   region = smem + db * 32768; }
        else if (h == 1) { mat = Bb; ldm = ldb; rb = colBase; halfRow = 0;   region = smem + 65536 + db * 32768; }
        else if (h == 2) { mat = Bb; ldm = ldb; rb = colBase; halfRow = 128; region = smem + 65536 + db * 32768; }
        else             { mat = Ab; ldm = lda; rb = rowBase; halfRow = 128; region = smem + db * 32768; }
#pragma unroll
        for (int i = 0; i < 2; i++) {
            int o    = ((i * 8 + w) << 10) + lane * 16;
            int r    = o >> 7;
            int slot = (o >> 4) & 7;
            const u16* g = mat + (size_t)(rb + halfRow + r) * ldm + kt +
                           ((slot ^ (r & 7)) << 3);
            gld16(g, region + halfRow * 128 + ((i * 8 + w) << 10));
        }
    };
    auto ldA = [&](int db, int row, int ks) -> bf16x8 {
        int byte = db * 32768 + row * 128 + ((((ks << 2) | (lane >> 4)) ^ (row & 7)) << 4);
        return *(const bf16x8*)(smem + byte);
    };
    auto ldB = [&](int db, int row, int ks) -> bf16x8 {
        int byte = 65536 + db * 32768 + row * 128 + ((((ks << 2) | (lane >> 4)) ^ (row & 7)) << 4);
        return *(const bf16x8*)(smem + byte);
    };

    f32x4 acc[8][4] = {};
    bf16x8 aF[4][2], b0[2][2], b1[2][2];

    stage(0, 0); stage(0, 3); stage(0, 1); stage(0, 2);
    stage(1, 1); stage(1, 2);
    __builtin_amdgcn_sched_barrier(0);
    asm volatile("s_waitcnt vmcnt(4)" ::: "memory");
    __builtin_amdgcn_sched_barrier(0);
    __builtin_amdgcn_s_barrier();

    for (int t = 0; t < NT; ++t) {
        const int db = t & 1;
        // ---- P1: read A-low + B-low; stage(t+1, Ah0); MFMA quad (0,0) ----
#pragma unroll
        for (int m = 0; m < 4; m++)
#pragma unroll
            for (int ks = 0; ks < 2; ks++)
                aF[m][ks] = ldA(db, wm * 128 + m * 16 + aRow, ks);
#pragma unroll
        for (int n = 0; n < 2; n++)
#pragma unroll
            for (int ks = 0; ks < 2; ks++)
                b0[n][ks] = ldB(db, wn * 64 + n * 16 + aRow, ks);
        stage(t + 1, 0);
        __builtin_amdgcn_s_barrier();
        asm volatile("s_waitcnt lgkmcnt(0)" ::: "memory");
        __builtin_amdgcn_sched_barrier(0);
        __builtin_amdgcn_s_setprio(1);
#pragma unroll
        for (int ks = 0; ks < 2; ks++)
#pragma unroll
            for (int m = 0; m < 4; m++)
#pragma unroll
                for (int n = 0; n < 2; n++)
                    acc[m][n] = __builtin_amdgcn_mfma_f32_16x16x32_bf16(
                        aF[m][ks], b0[n][ks], acc[m][n], 0, 0, 0);
        __builtin_amdgcn_s_setprio(0);
        // ---- P2: read B-high; stage(t+1, Ah1); MFMA quad (0,1) ----
#pragma unroll
        for (int n = 0; n < 2; n++)
#pragma unroll
            for (int ks = 0; ks < 2; ks++)
                b1[n][ks] = ldB(db, wn * 64 + (n + 2) * 16 + aRow, ks);
        stage(t + 1, 3);
        __builtin_amdgcn_s_barrier();
        asm volatile("s_waitcnt lgkmcnt(0)" ::: "memory");
        __builtin_amdgcn_sched_barrier(0);
        __builtin_amdgcn_s_setprio(1);
#pragma unroll
        for (int ks = 0; ks < 2; ks++)
#pragma unroll
            for (int m = 0; m < 4; m++)
#pragma unroll
                for (int n = 0; n < 2; n++)
                    acc[m][n + 2] = __builtin_amdgcn_mfma_f32_16x16x32_bf16(
                        aF[m][ks], b1[n][ks], acc[m][n + 2], 0, 0, 0);
        __builtin_amdgcn_s_setprio(0);
        // ---- P3: read A-high; MFMA quad (1,1) ----
#pragma unroll
        for (int m = 0; m < 4; m++)
#pragma unroll
            for (int ks = 0; ks < 2; ks++)
                aF[m][ks] = ldA(db, wm * 128 + (m + 4) * 16 + aRow, ks);
        __builtin_amdgcn_s_barrier();
        asm volatile("s_waitcnt lgkmcnt(0)" ::: "memory");
        __builtin_amdgcn_sched_barrier(0);
        __builtin_amdgcn_s_setprio(1);
#pragma unroll
        for (int ks = 0; ks < 2; ks++)
#pragma unroll
            for (int m = 0; m < 4; m++)
#pragma unroll
                for (int n = 0; n < 2; n++)
                    acc[m + 4][n + 2] = __builtin_amdgcn_mfma_f32_16x16x32_bf16(
                        aF[m][ks], b1[n][ks], acc[m + 4][n + 2], 0, 0, 0);
        __builtin_amdgcn_s_setprio(0);
        // ---- P4: stage(t+2, Bh0)+(t+2, Bh1); vmcnt; MFMA quad (1,0) ----
        stage(t + 2, 1);
        stage(t + 2, 2);
        __builtin_amdgcn_sched_barrier(0);
        if (t + 2 < NT) { asm volatile("s_waitcnt vmcnt(4)" ::: "memory"); }
        else            { asm volatile("s_waitcnt vmcnt(0)" ::: "memory"); }
        __builtin_amdgcn_sched_barrier(0);
        __builtin_amdgcn_s_barrier();
        __builtin_amdgcn_s_setprio(1);
#pragma unroll
        for (int ks = 0; ks < 2; ks++)
#pragma unroll
            for (int m = 0; m < 4; m++)
#pragma unroll
                for (int n = 0; n < 2; n++)
                    acc[m + 4][n] = __builtin_amdgcn_mfma_f32_16x16x32_bf16(
                        aF[m][ks], b0[n][ks], acc[m + 4][n], 0, 0, 0);
        __builtin_amdgcn_s_setprio(0);
    }

    // epilogue: C/D layout col = lane&15, row = (lane>>4)*4 + j
    const int row0 = rowBase + wm * 128 + ((lane >> 4) << 2);
    const int col0 = colBase + wn * 64 + (lane & 15);
    long long cb = (long long)bz * sC;
    if (EPI == 0) {
#pragma unroll
        for (int m = 0; m < 8; m++)
#pragma unroll
            for (int n = 0; n < 4; n++) {
                f32x4 v = acc[m][n];
#pragma unroll
                for (int j = 0; j < 4; j++) {
                    size_t idx = (size_t)(row0 + m * 16 + j) * ldc + (col0 + n * 16);
                    ((u16*)Cv)[cb + idx] = f2bf(v[j] * scale);
                }
            }
    } else {  // EPI == 2: exp + row partial sums
        float* dz = denom + (long long)bz * 2048;
#pragma unroll
        for (int m = 0; m < 8; m++) {
#pragma unroll
            for (int j = 0; j < 4; j++) {
                const int row = row0 + m * 16 + j;
                float rs = 0.f;
#pragma unroll
                for (int n = 0; n < 4; n++) {
                    float e = __expf(fminf(acc[m][n][j] * scale, 60.f));
                    rs += e;
                    ((u16*)Cv)[cb + (size_t)row * ldc + (col0 + n * 16)] = f2bf(e);
                }
#pragma unroll
                for (int off = 1; off < 16; off <<= 1) rs += __shfl_xor(rs, off);
                if ((lane & 15) == 0) atomicAdd(&dz[row], rs);
            }
        }
    }
}

// ======== 256x128 single-barrier-per-phase bf16 GEMM body ========
// EPI 0: bf16 store (VT projection). EPI 3: fp32 acc/denom (PV).
template <int EPI>
__device__ __forceinline__ void g128_body(
    int bx, int by, int bz, char* smem,
    const u16* __restrict__ A, const u16* __restrict__ Bm, void* __restrict__ Cv,
    int K, int lda, int ldb, int ldc,
    long long sA, long long sB, long long sC, float scale,
    const float* __restrict__ denom) {
    const u16* Ab = A + (long long)bz * sA;
    const u16* Bb = Bm + (long long)bz * sB;

    const int tid  = threadIdx.x;
    const int lane = tid & 63;
    const int w    = tid >> 6;
    const int wm   = w >> 1;   // 0..3
    const int wn   = w & 1;    // 0..1
    const int rowBase = bx << 8;
    const int colBase = by << 7;
    const int NT = K >> 6;
    const int aRow = lane & 15;

    auto stage = [&](int tile, int h) {
        if (tile >= NT) return;
        const int db = tile & 1;
        const int kt = tile << 6;
        if (h == 0 || h == 3) {
            const int halfRow = (h == 0) ? 0 : 128;
            char* region = smem + db * 32768;
#pragma unroll
            for (int i = 0; i < 2; i++) {
                int o    = i * 8192 + tid * 16;
                int r    = o >> 7;
                int slot = (o >> 4) & 7;
                const u16* g = Ab + (size_t)(rowBase + halfRow + r) * lda + kt +
                               ((slot ^ (r & 7)) << 3);
                gld16(g, region + halfRow * 128 + i * 8192 + (w << 10));
            }
        } else {
            const int halfRow = (h == 1) ? 0 : 64;
            char* region = smem + 65536 + db * 16384;
            int o    = tid * 16;
            int r    = o >> 7;
            int slot = (o >> 4) & 7;
            const u16* g = Bb + (size_t)(colBase + halfRow + r) * ldb + kt +
                           ((slot ^ (r & 7)) << 3);
            gld16(g, region + halfRow * 128 + (w << 10));
        }
    };
    auto ldA = [&](int db, int row, int ks) -> bf16x8 {
        int byte = db * 32768 + row * 128 + ((((ks << 2) | (lane >> 4)) ^ (row & 7)) << 4);
        return *(const bf16x8*)(smem + byte);
    };
    auto ldB = [&](int db, int row, int ks) -> bf16x8 {
        int byte = 65536 + db * 16384 + row * 128 + ((((ks << 2) | (lane >> 4)) ^ (row & 7)) << 4);
        return *(const bf16x8*)(smem + byte);
    };

    f32x4 acc[4][4] = {};
    bf16x8 aF[2][2], b0[2][2], b1[2][2];

    stage(0, 0); stage(0, 3); stage(0, 1); stage(0, 2);
    stage(1, 1); stage(1, 2);
    __builtin_amdgcn_sched_barrier(0);
    asm volatile("s_waitcnt vmcnt(2)" ::: "memory");
    __builtin_amdgcn_sched_barrier(0);
    __builtin_amdgcn_s_barrier();

    for (int t = 0; t < NT; ++t) {
        const int db = t & 1;
        // ---- P1: read a[m01] + b[n01]; stage(t+1, Ah0); MFMA m01 x n01 ----
#pragma unroll
        for (int m = 0; m < 2; m++)
#pragma unroll
            for (int ks = 0; ks < 2; ks++)
                aF[m][ks] = ldA(db, wm * 64 + m * 16 + aRow, ks);
#pragma unroll
        for (int n = 0; n < 2; n++)
#pragma unroll
            for (int ks = 0; ks < 2; ks++)
                b0[n][ks] = ldB(db, wn * 64 + n * 16 + aRow, ks);
        stage(t + 1, 0);
        __builtin_amdgcn_s_barrier();
        asm volatile("s_waitcnt lgkmcnt(0)" ::: "memory");
        __builtin_amdgcn_sched_barrier(0);
        __builtin_amdgcn_s_setprio(1);
#pragma unroll
        for (int ks = 0; ks < 2; ks++)
#pragma unroll
            for (int m = 0; m < 2; m++)
#pragma unroll
                for (int n = 0; n < 2; n++)
                    acc[m][n] = __builtin_amdgcn_mfma_f32_16x16x32_bf16(
                        aF[m][ks], b0[n][ks], acc[m][n], 0, 0, 0);
        __builtin_amdgcn_s_setprio(0);
        // ---- P2: read b[n23]; stage(t+1, Ah1); MFMA m01 x n23 ----
#pragma unroll
        for (int n = 0; n < 2; n++)
#pragma unroll
            for (int ks = 0; ks < 2; ks++)
                b1[n][ks] = ldB(db, wn * 64 + (n + 2) * 16 + aRow, ks);
        stage(t + 1, 3);
        __builtin_amdgcn_s_barrier();
        asm volatile("s_waitcnt lgkmcnt(0)" ::: "memory");
        __builtin_amdgcn_sched_barrier(0);
        __builtin_amdgcn_s_setprio(1);
#pragma unroll
        for (int ks = 0; ks < 2; ks++)
#pragma unroll
            for (int m = 0; m < 2; m++)
#pragma unroll
                for (int n = 0; n < 2; n++)
                    acc[m][n + 2] = __builtin_amdgcn_mfma_f32_16x16x32_bf16(
                        aF[m][ks], b1[n][ks], acc[m][n + 2], 0, 0, 0);
        __builtin_amdgcn_s_setprio(0);
        // ---- P3: read a[m23]; MFMA m23 x n23 ----
#pragma unroll
        for (int m = 0; m < 2; m++)
#pragma unroll
            for (int ks = 0; ks < 2; ks++)
                aF[m][ks] = ldA(db, wm * 64 + (m + 2) * 16 + aRow, ks);
        __builtin_amdgcn_s_barrier();
        asm volatile("s_waitcnt lgkmcnt(0)" ::: "memory");
        __builtin_amdgcn_sched_barrier(0);
        __builtin_amdgcn_s_setprio(1);
#pragma unroll
        for (int ks = 0; ks < 2; ks++)
#pragma unroll
            for (int m = 0; m < 2; m++)
#pragma unroll
                for (int n = 0; n < 2; n++)
                    acc[m + 2][n + 2] = __builtin_amdgcn_mfma_f32_16x16x32_bf16(
                        aF[m][ks], b1[n][ks], acc[m + 2][n + 2], 0, 0, 0);
        __builtin_amdgcn_s_setprio(0);
        // ---- P4: stage(t+2, Bh0)+(t+2, Bh1); vmcnt; MFMA m23 x n01 ----
        stage(t + 2, 1);
        stage(t + 2, 2);
        __builtin_amdgcn_sched_barrier(0);
        if (t + 2 < NT) { asm volatile("s_waitcnt vmcnt(2)" ::: "memory"); }
        else            { asm volatile("s_waitcnt vmcnt(0)" ::: "memory"); }
        __builtin_amdgcn_sched_barrier(0);
        __builtin_amdgcn_s_barrier();
        __builtin_amdgcn_s_setprio(1);
#pragma unroll
        for (int ks = 0; ks < 2; ks++)
#pragma unroll
            for (int m = 0; m < 2; m++)
#pragma unroll
                for (int n = 0; n < 2; n++)
                    acc[m + 2][n] = __builtin_amdgcn_mfma_f32_16x16x32_bf16(
                        aF[m][ks], b0[n][ks], acc[m + 2][n], 0, 0, 0);
        __builtin_amdgcn_s_setprio(0);
    }

    const int row0 = rowBase + wm * 64 + ((lane >> 4) << 2);
    const int col0 = colBase + wn * 64 + (lane & 15);
    long long cb = (long long)bz * sC;
    if (EPI == 0) {
#pragma unroll
        for (int m = 0; m < 4; m++)
#pragma unroll
            for (int n = 0; n < 4; n++) {
                f32x4 v = acc[m][n];
#pragma unroll
                for (int j = 0; j < 4; j++) {
                    size_t idx = (size_t)(row0 + m * 16 + j) * ldc + (col0 + n * 16);
                    ((u16*)Cv)[cb + idx] = f2bf(v[j] * scale);
                }
            }
    } else {  // EPI == 3: fp32 out, divide by softmax denominator
        const float* dz = denom + (long long)bz * 2048;
        float inv[4][4];
#pragma unroll
        for (int m = 0; m < 4; m++)
#pragma unroll
            for (int j = 0; j < 4; j++)
                inv[m][j] = 1.0f / dz[row0 + m * 16 + j];
#pragma unroll
        for (int m = 0; m < 4; m++)
#pragma unroll
            for (int n = 0; n < 4; n++) {
                f32x4 v = acc[m][n];
#pragma unroll
                for (int j = 0; j < 4; j++) {
                    size_t idx = (size_t)(row0 + m * 16 + j) * ldc + (col0 + n * 16);
                    ((float*)Cv)[cb + idx] = v[j] * inv[m][j];
                }
            }
    }
}

// ---- global wrappers ----
template <int EPI>
__global__ __launch_bounds__(512, 1) void gemm256(
    const u16* __restrict__ A, const u16* __restrict__ Bm, void* __restrict__ Cv,
    int K, int lda, int ldb, int ldc,
    long long sA, long long sB, long long sC, float scale,
    float* __restrict__ denom) {
    extern __shared__ char smem[];
    int bx, by, bz;
    xcd_map(bx, by, bz);
    g256_body<EPI>(bx, by, bz, smem, A, Bm, Cv, K, lda, ldb, ldc, sA, sB, sC, scale, denom);
}

template <int EPI>
__global__ __launch_bounds__(512, 1) void gemm256n128(
    const u16* __restrict__ A, const u16* __restrict__ Bm, void* __restrict__ Cv,
    int K, int lda, int ldb, int ldc,
    long long sA, long long sB, long long sC, float scale,
    const float* __restrict__ denom) {
    extern __shared__ char smem[];
    int bx, by, bz;
    xcd_map(bx, by, bz);
    g128_body<EPI>(bx, by, bz, smem, A, Bm, Cv, K, lda, ldb, ldc, sA, sB, sC, scale, denom);
}

// ---- fused projections: QKproj (L<256, 256x256 body) + VTproj (L>=256, 256x128) ----
// One 512-block dispatch: freed CUs pick up VT blocks during QK's tail instead
// of idling through a dispatch boundary. L=(F&7)*64+(F>>3) is bijective and
// gives each XCD a contiguous 64-block logical chunk (T1 preserved).
__global__ __launch_bounds__(512, 1) void proj_fused(
    const u16* __restrict__ xb, const u16* __restrict__ Wqk, u16* __restrict__ QK,
    const u16* __restrict__ Wvb, u16* __restrict__ VT) {
    extern __shared__ char smem[];
    const int F = blockIdx.x;
    const int L = (F & 7) * 64 + (F >> 3);
    if (L < 256) {
        // [Q|K] = x @ [Wq|Wk]^T : M=8192, N=2048, K=1024; grid (32,8)
        g256_body<0>(L % 32, L / 32, 0, smem, xb, Wqk, QK,
                     1024, 1024, 1024, 2048, 0, 0, 0, 1.0f, nullptr);
    } else {
        // V^T = Wv @ x^T : M=1024, N=8192, K=1024; grid (4,64)
        const int L2 = L - 256;
        g128_body<0>(L2 % 4, L2 / 4, 0, smem, Wvb, xb, VT,
                     1024, 1024, 1024, 8192, 0, 0, 0, 1.0f, nullptr);
    }
}

// ---------------- launch ----------------
extern "C" void kernel_launch(void* const* d_in, const int* in_sizes, int n_in,
                              void* d_out, int out_size, void* d_ws, size_t ws_size,
                              hipStream_t stream) {
    const float* x  = (const float*)d_in[0];
    const float* Wk = (const float*)d_in[1];
    const float* Wq = (const float*)d_in[2];
    const float* Wv = (const float*)d_in[3];
    float* out = (float*)d_out;
    char* ws = (char*)d_ws;
    const size_t MB = 1u << 20;

    u16* xb    = (u16*)(ws);             // 16MB [8192][1024]
    u16* Wqk   = (u16*)(ws + 16 * MB);   // 4MB  [2048][1024]: rows 0-1023 Wq, 1024-2047 Wk
    u16* Wvb   = (u16*)(ws + 20 * MB);   // 2MB
    float* den = (float*)(ws + 24 * MB); // 32KB [4][2048] softmax denominators
    u16* QK    = (u16*)(ws + 64 * MB);   // 32MB [8192][2048]: cols 0-1023 Q, 1024-2047 K
    u16* VT    = (u16*)(ws + 96 * MB);   // 16MB [1024][8192]: VT[o][b*2048+s]
    u16* Pb    = (u16*)(ws + 112 * MB);  // 32MB [4][2048][2048] unnormalized exp(scores)

    const long long SS = 2048LL * 2048;

    hipFuncSetAttribute((const void*)proj_fused, hipFuncAttributeMaxDynamicSharedMemorySize, 131072);
    hipFuncSetAttribute((const void*)gemm256<2>, hipFuncAttributeMaxDynamicSharedMemorySize, 131072);
    hipFuncSetAttribute((const void*)gemm256n128<3>, hipFuncAttributeMaxDynamicSharedMemorySize, 98304);

    // fused prologue: x/Wq/Wk/Wv casts + den zero in one dispatch
    prep_kernel<<<2048, 256, 0, stream>>>(x, Wq, Wk, Wv, xb, Wqk, Wvb, den);

    // QKproj + VTproj fused: 512 blocks, one dispatch
    proj_fused<<<512, 512, 131072, stream>>>(xb, Wqk, QK, Wvb, VT);

    // P_unnorm = exp((Q @ K^T)/32), denom += row sums : per batch (256 blocks)
    gemm256<2><<<dim3(8, 8, 4), 512, 131072, stream>>>(
        QK, QK + 1024, Pb, 1024, 2048, 2048, 2048, SS, SS, SS, 0.03125f, den);
    // ctx = (P_unnorm @ (V^T)^T) / denom : per batch (256 blocks)
    gemm256n128<3><<<dim3(8, 8, 4), 512, 98304, stream>>>(
        Pb, VT, out, 2048, 2048, 8192, 1024, SS, 2048LL, 2048LL * 1024, 1.0f, den);
}

// Round 16
// 146.265 us; speedup vs baseline: 1.0517x; 1.0517x over previous
//
#include <hip/hip_runtime.h>

typedef unsigned short u16;
typedef __attribute__((ext_vector_type(4))) float f32x4;
typedef __attribute__((ext_vector_type(8))) short bf16x8;
typedef __attribute__((ext_vector_type(4))) u16 u16x4;
typedef __attribute__((ext_vector_type(8))) u16 u16x8;

__device__ __forceinline__ u16 f2bf(float f) {
    unsigned u = __float_as_uint(f);
    unsigned r = (u + 0x7FFFu + ((u >> 16) & 1u)) >> 16;
    return (u16)r;
}

__device__ __forceinline__ void gld16(const void* g, void* l) {
    __builtin_amdgcn_global_load_lds(
        (const __attribute__((address_space(1))) unsigned*)g,
        (__attribute__((address_space(3))) unsigned*)l,
        16, 0, 0);
}

// XCD-aware bijective block remap (T1). Verified R11: scores FETCH 74.7->27.7MB.
// R15 lesson: do NOT mix different GEMM bodies in one dispatch — their combined
// working sets thrash the per-XCD L2 (FETCH 84MB) and erase T1's gain.
__device__ __forceinline__ void xcd_map(int& bx, int& by, int& bz) {
    const int gx = gridDim.x, gxy = gridDim.x * gridDim.y;
    const int F = blockIdx.x + gx * (blockIdx.y + gridDim.y * blockIdx.z);
    const int cpx = (gxy * gridDim.z) >> 3;
    const int L = (F & 7) * cpx + (F >> 3);
    bz = L / gxy;
    const int r = L % gxy;
    by = r / gx;
    bx = r % gx;
}

// ---------------- fused prologue: all casts + den zero, ONE launch ----------------
// f32x4-unit ranges: x[0,2097152) Wq[..+262144) Wk[..] Wv[..] den-zero[..+2048)
__global__ __launch_bounds__(256) void prep_kernel(
    const float* __restrict__ x, const float* __restrict__ Wq,
    const float* __restrict__ Wk, const float* __restrict__ Wv,
    u16* __restrict__ xb, u16* __restrict__ wqk, u16* __restrict__ wvb,
    float* __restrict__ den) {
    const int NX = 2097152, NW = 262144;
    const int total = NX + 3 * NW + 2048;
    int i = blockIdx.x * blockDim.x + threadIdx.x;
    int stride = gridDim.x * blockDim.x;
    for (; i < total; i += stride) {
        const float* src; u16* dst; int j;
        if (i < NX)               { src = x;  dst = xb;            j = i; }
        else if (i < NX + NW)     { src = Wq; dst = wqk;           j = i - NX; }
        else if (i < NX + 2 * NW) { src = Wk; dst = wqk + 1048576; j = i - NX - NW; }
        else if (i < NX + 3 * NW) { src = Wv; dst = wvb;           j = i - NX - 2 * NW; }
        else { ((f32x4*)den)[i - NX - 3 * NW] = f32x4{0.f, 0.f, 0.f, 0.f}; continue; }
        f32x4 v = ((const f32x4*)src)[j];
        u16x4 o;
        o[0] = f2bf(v[0]); o[1] = f2bf(v[1]); o[2] = f2bf(v[2]); o[3] = f2bf(v[3]);
        ((u16x4*)dst)[j] = o;
    }
}

// ======== 256x256 single-barrier-per-phase bf16 GEMM: C = A[M,K]*B[N,K]^T ========
// R7-proven schedule + T1. 8 waves (2M x 4N), BK=64, LDS 128KB dbuf,
// XOR swizzle both-sides, gap-2 stage slots, vmcnt(4).
// EPI 0: C = bf16(acc*scale)   (QK projection)
// EPI 2: P_unnorm = bf16(exp(acc*scale)); atomicAdd row sums into denom.
template <int EPI>
__global__ __launch_bounds__(512, 1) void gemm256(
    const u16* __restrict__ A, const u16* __restrict__ Bm, void* __restrict__ Cv,
    int K, int lda, int ldb, int ldc,
    long long sA, long long sB, long long sC, float scale,
    float* __restrict__ denom) {
    extern __shared__ char smem[];
    int bx, by, bz;
    xcd_map(bx, by, bz);
    const u16* Ab = A + (long long)bz * sA;
    const u16* Bb = Bm + (long long)bz * sB;

    const int tid  = threadIdx.x;
    const int lane = tid & 63;
    const int w    = tid >> 6;
    const int wm   = w >> 2;   // 0..1
    const int wn   = w & 3;    // 0..3
    const int rowBase = bx << 8;
    const int colBase = by << 8;
    const int NT = K >> 6;     // requires NT >= 2
    const int aRow = lane & 15;

    auto stage = [&](int tile, int h) {
        if (tile >= NT) return;
        const int db = tile & 1;
        const int kt = tile << 6;
        const u16* mat; int ldm, rb, halfRow; char* region;
        if (h == 0)      { mat = Ab; ldm = lda; rb = rowBase; halfRow = 0;   region = smem + db * 32768; }
        else if (h == 1) { mat = Bb; ldm = ldb; rb = colBase; halfRow = 0;   region = smem + 65536 + db * 32768; }
        else if (h == 2) { mat = Bb; ldm = ldb; rb = colBase; halfRow = 128; region = smem + 65536 + db * 32768; }
        else             { mat = Ab; ldm = lda; rb = rowBase; halfRow = 128; region = smem + db * 32768; }
#pragma unroll
        for (int i = 0; i < 2; i++) {
            int o    = ((i * 8 + w) << 10) + lane * 16;
            int r    = o >> 7;
            int slot = (o >> 4) & 7;
            const u16* g = mat + (size_t)(rb + halfRow + r) * ldm + kt +
                           ((slot ^ (r & 7)) << 3);
            gld16(g, region + halfRow * 128 + ((i * 8 + w) << 10));
        }
    };
    auto ldA = [&](int db, int row, int ks) -> bf16x8 {
        int byte = db * 32768 + row * 128 + ((((ks << 2) | (lane >> 4)) ^ (row & 7)) << 4);
        return *(const bf16x8*)(smem + byte);
    };
    auto ldB = [&](int db, int row, int ks) -> bf16x8 {
        int byte = 65536 + db * 32768 + row * 128 + ((((ks << 2) | (lane >> 4)) ^ (row & 7)) << 4);
        return *(const bf16x8*)(smem + byte);
    };

    f32x4 acc[8][4] = {};
    bf16x8 aF[4][2], b0[2][2], b1[2][2];

    stage(0, 0); stage(0, 3); stage(0, 1); stage(0, 2);
    stage(1, 1); stage(1, 2);
    __builtin_amdgcn_sched_barrier(0);
    asm volatile("s_waitcnt vmcnt(4)" ::: "memory");
    __builtin_amdgcn_sched_barrier(0);
    __builtin_amdgcn_s_barrier();

    for (int t = 0; t < NT; ++t) {
        const int db = t & 1;
        // ---- P1: read A-low + B-low; stage(t+1, Ah0); MFMA quad (0,0) ----
#pragma unroll
        for (int m = 0; m < 4; m++)
#pragma unroll
            for (int ks = 0; ks < 2; ks++)
                aF[m][ks] = ldA(db, wm * 128 + m * 16 + aRow, ks);
#pragma unroll
        for (int n = 0; n < 2; n++)
#pragma unroll
            for (int ks = 0; ks < 2; ks++)
                b0[n][ks] = ldB(db, wn * 64 + n * 16 + aRow, ks);
        stage(t + 1, 0);
        __builtin_amdgcn_s_barrier();
        asm volatile("s_waitcnt lgkmcnt(0)" ::: "memory");
        __builtin_amdgcn_sched_barrier(0);
        __builtin_amdgcn_s_setprio(1);
#pragma unroll
        for (int ks = 0; ks < 2; ks++)
#pragma unroll
            for (int m = 0; m < 4; m++)
#pragma unroll
                for (int n = 0; n < 2; n++)
                    acc[m][n] = __builtin_amdgcn_mfma_f32_16x16x32_bf16(
                        aF[m][ks], b0[n][ks], acc[m][n], 0, 0, 0);
        __builtin_amdgcn_s_setprio(0);
        // ---- P2: read B-high; stage(t+1, Ah1); MFMA quad (0,1) ----
#pragma unroll
        for (int n = 0; n < 2; n++)
#pragma unroll
            for (int ks = 0; ks < 2; ks++)
                b1[n][ks] = ldB(db, wn * 64 + (n + 2) * 16 + aRow, ks);
        stage(t + 1, 3);
        __builtin_amdgcn_s_barrier();
        asm volatile("s_waitcnt lgkmcnt(0)" ::: "memory");
        __builtin_amdgcn_sched_barrier(0);
        __builtin_amdgcn_s_setprio(1);
#pragma unroll
        for (int ks = 0; ks < 2; ks++)
#pragma unroll
            for (int m = 0; m < 4; m++)
#pragma unroll
                for (int n = 0; n < 2; n++)
                    acc[m][n + 2] = __builtin_amdgcn_mfma_f32_16x16x32_bf16(
                        aF[m][ks], b1[n][ks], acc[m][n + 2], 0, 0, 0);
        __builtin_amdgcn_s_setprio(0);
        // ---- P3: read A-high; MFMA quad (1,1) ----
#pragma unroll
        for (int m = 0; m < 4; m++)
#pragma unroll
            for (int ks = 0; ks < 2; ks++)
                aF[m][ks] = ldA(db, wm * 128 + (m + 4) * 16 + aRow, ks);
        __builtin_amdgcn_s_barrier();
        asm volatile("s_waitcnt lgkmcnt(0)" ::: "memory");
        __builtin_amdgcn_sched_barrier(0);
        __builtin_amdgcn_s_setprio(1);
#pragma unroll
        for (int ks = 0; ks < 2; ks++)
#pragma unroll
            for (int m = 0; m < 4; m++)
#pragma unroll
                for (int n = 0; n < 2; n++)
                    acc[m + 4][n + 2] = __builtin_amdgcn_mfma_f32_16x16x32_bf16(
                        aF[m][ks], b1[n][ks], acc[m + 4][n + 2], 0, 0, 0);
        __builtin_amdgcn_s_setprio(0);
        // ---- P4: stage(t+2, Bh0)+(t+2, Bh1); vmcnt; MFMA quad (1,0) ----
        stage(t + 2, 1);
        stage(t + 2, 2);
        __builtin_amdgcn_sched_barrier(0);
        if (t + 2 < NT) { asm volatile("s_waitcnt vmcnt(4)" ::: "memory"); }
        else            { asm volatile("s_waitcnt vmcnt(0)" ::: "memory"); }
        __builtin_amdgcn_sched_barrier(0);
        __builtin_amdgcn_s_barrier();
        __builtin_amdgcn_s_setprio(1);
#pragma unroll
        for (int ks = 0; ks < 2; ks++)
#pragma unroll
            for (int m = 0; m < 4; m++)
#pragma unroll
                for (int n = 0; n < 2; n++)
                    acc[m + 4][n] = __builtin_amdgcn_mfma_f32_16x16x32_bf16(
                        aF[m][ks], b0[n][ks], acc[m + 4][n], 0, 0, 0);
        __builtin_amdgcn_s_setprio(0);
    }

    // epilogue: C/D layout col = lane&15, row = (lane>>4)*4 + j
    const int row0 = rowBase + wm * 128 + ((lane >> 4) << 2);
    const int col0 = colBase + wn * 64 + (lane & 15);
    long long cb = (long long)bz * sC;
    if (EPI == 0) {
#pragma unroll
        for (int m = 0; m < 8; m++)
#pragma unroll
            for (int n = 0; n < 4; n++) {
                f32x4 v = acc[m][n];
#pragma unroll
                for (int j = 0; j < 4; j++) {
                    size_t idx = (size_t)(row0 + m * 16 + j) * ldc + (col0 + n * 16);
                    ((u16*)Cv)[cb + idx] = f2bf(v[j] * scale);
                }
            }
    } else {  // EPI == 2: exp + row partial sums
        float* dz = denom + (long long)bz * 2048;
#pragma unroll
        for (int m = 0; m < 8; m++) {
#pragma unroll
            for (int j = 0; j < 4; j++) {
                const int row = row0 + m * 16 + j;
                float rs = 0.f;
#pragma unroll
                for (int n = 0; n < 4; n++) {
                    float e = __expf(fminf(acc[m][n][j] * scale, 60.f));
                    rs += e;
                    ((u16*)Cv)[cb + (size_t)row * ldc + (col0 + n * 16)] = f2bf(e);
                }
#pragma unroll
                for (int off = 1; off < 16; off <<= 1) rs += __shfl_xor(rs, off);
                if ((lane & 15) == 0) atomicAdd(&dz[row], rs);
            }
        }
    }
}

// ======== 256x128 single-barrier-per-phase bf16 GEMM + T1 ========
// 8 waves (4M x 2N), per-wave 64x64. LDS 96KB: A 2x32KB, B 2x16KB.
// EPI 0: bf16 store (VT projection). EPI 3: fp32 acc/denom (PV).
template <int EPI>
__global__ __launch_bounds__(512, 1) void gemm256n128(
    const u16* __restrict__ A, const u16* __restrict__ Bm, void* __restrict__ Cv,
    int K, int lda, int ldb, int ldc,
    long long sA, long long sB, long long sC, float scale,
    const float* __restrict__ denom) {
    extern __shared__ char smem[];
    int bx, by, bz;
    xcd_map(bx, by, bz);
    const u16* Ab = A + (long long)bz * sA;
    const u16* Bb = Bm + (long long)bz * sB;

    const int tid  = threadIdx.x;
    const int lane = tid & 63;
    const int w    = tid >> 6;
    const int wm   = w >> 1;   // 0..3
    const int wn   = w & 1;    // 0..1
    const int rowBase = bx << 8;
    const int colBase = by << 7;
    const int NT = K >> 6;
    const int aRow = lane & 15;

    auto stage = [&](int tile, int h) {
        if (tile >= NT) return;
        const int db = tile & 1;
        const int kt = tile << 6;
        if (h == 0 || h == 3) {
            const int halfRow = (h == 0) ? 0 : 128;
            char* region = smem + db * 32768;
#pragma unroll
            for (int i = 0; i < 2; i++) {
                int o    = i * 8192 + tid * 16;
                int r    = o >> 7;
                int slot = (o >> 4) & 7;
                const u16* g = Ab + (size_t)(rowBase + halfRow + r) * lda + kt +
                               ((slot ^ (r & 7)) << 3);
                gld16(g, region + halfRow * 128 + i * 8192 + (w << 10));
            }
        } else {
            const int halfRow = (h == 1) ? 0 : 64;
            char* region = smem + 65536 + db * 16384;
            int o    = tid * 16;
            int r    = o >> 7;
            int slot = (o >> 4) & 7;
            const u16* g = Bb + (size_t)(colBase + halfRow + r) * ldb + kt +
                           ((slot ^ (r & 7)) << 3);
            gld16(g, region + halfRow * 128 + (w << 10));
        }
    };
    auto ldA = [&](int db, int row, int ks) -> bf16x8 {
        int byte = db * 32768 + row * 128 + ((((ks << 2) | (lane >> 4)) ^ (row & 7)) << 4);
        return *(const bf16x8*)(smem + byte);
    };
    auto ldB = [&](int db, int row, int ks) -> bf16x8 {
        int byte = 65536 + db * 16384 + row * 128 + ((((ks << 2) | (lane >> 4)) ^ (row & 7)) << 4);
        return *(const bf16x8*)(smem + byte);
    };

    f32x4 acc[4][4] = {};
    bf16x8 aF[2][2], b0[2][2], b1[2][2];

    stage(0, 0); stage(0, 3); stage(0, 1); stage(0, 2);
    stage(1, 1); stage(1, 2);
    __builtin_amdgcn_sched_barrier(0);
    asm volatile("s_waitcnt vmcnt(2)" ::: "memory");
    __builtin_amdgcn_sched_barrier(0);
    __builtin_amdgcn_s_barrier();

    for (int t = 0; t < NT; ++t) {
        const int db = t & 1;
        // ---- P1: read a[m01] + b[n01]; stage(t+1, Ah0); MFMA m01 x n01 ----
#pragma unroll
        for (int m = 0; m < 2; m++)
#pragma unroll
            for (int ks = 0; ks < 2; ks++)
                aF[m][ks] = ldA(db, wm * 64 + m * 16 + aRow, ks);
#pragma unroll
        for (int n = 0; n < 2; n++)
#pragma unroll
            for (int ks = 0; ks < 2; ks++)
                b0[n][ks] = ldB(db, wn * 64 + n * 16 + aRow, ks);
        stage(t + 1, 0);
        __builtin_amdgcn_s_barrier();
        asm volatile("s_waitcnt lgkmcnt(0)" ::: "memory");
        __builtin_amdgcn_sched_barrier(0);
        __builtin_amdgcn_s_setprio(1);
#pragma unroll
        for (int ks = 0; ks < 2; ks++)
#pragma unroll
            for (int m = 0; m < 2; m++)
#pragma unroll
                for (int n = 0; n < 2; n++)
                    acc[m][n] = __builtin_amdgcn_mfma_f32_16x16x32_bf16(
                        aF[m][ks], b0[n][ks], acc[m][n], 0, 0, 0);
        __builtin_amdgcn_s_setprio(0);
        // ---- P2: read b[n23]; stage(t+1, Ah1); MFMA m01 x n23 ----
#pragma unroll
        for (int n = 0; n < 2; n++)
#pragma unroll
            for (int ks = 0; ks < 2; ks++)
                b1[n][ks] = ldB(db, wn * 64 + (n + 2) * 16 + aRow, ks);
        stage(t + 1, 3);
        __builtin_amdgcn_s_barrier();
        asm volatile("s_waitcnt lgkmcnt(0)" ::: "memory");
        __builtin_amdgcn_sched_barrier(0);
        __builtin_amdgcn_s_setprio(1);
#pragma unroll
        for (int ks = 0; ks < 2; ks++)
#pragma unroll
            for (int m = 0; m < 2; m++)
#pragma unroll
                for (int n = 0; n < 2; n++)
                    acc[m][n + 2] = __builtin_amdgcn_mfma_f32_16x16x32_bf16(
                        aF[m][ks], b1[n][ks], acc[m][n + 2], 0, 0, 0);
        __builtin_amdgcn_s_setprio(0);
        // ---- P3: read a[m23]; MFMA m23 x n23 ----
#pragma unroll
        for (int m = 0; m < 2; m++)
#pragma unroll
            for (int ks = 0; ks < 2; ks++)
                aF[m][ks] = ldA(db, wm * 64 + (m + 2) * 16 + aRow, ks);
        __builtin_amdgcn_s_barrier();
        asm volatile("s_waitcnt lgkmcnt(0)" ::: "memory");
        __builtin_amdgcn_sched_barrier(0);
        __builtin_amdgcn_s_setprio(1);
#pragma unroll
        for (int ks = 0; ks < 2; ks++)
#pragma unroll
            for (int m = 0; m < 2; m++)
#pragma unroll
                for (int n = 0; n < 2; n++)
                    acc[m + 2][n + 2] = __builtin_amdgcn_mfma_f32_16x16x32_bf16(
                        aF[m][ks], b1[n][ks], acc[m + 2][n + 2], 0, 0, 0);
        __builtin_amdgcn_s_setprio(0);
        // ---- P4: stage(t+2, Bh0)+(t+2, Bh1); vmcnt; MFMA m23 x n01 ----
        stage(t + 2, 1);
        stage(t + 2, 2);
        __builtin_amdgcn_sched_barrier(0);
        if (t + 2 < NT) { asm volatile("s_waitcnt vmcnt(2)" ::: "memory"); }
        else            { asm volatile("s_waitcnt vmcnt(0)" ::: "memory"); }
        __builtin_amdgcn_sched_barrier(0);
        __builtin_amdgcn_s_barrier();
        __builtin_amdgcn_s_setprio(1);
#pragma unroll
        for (int ks = 0; ks < 2; ks++)
#pragma unroll
            for (int m = 0; m < 2; m++)
#pragma unroll
                for (int n = 0; n < 2; n++)
                    acc[m + 2][n] = __builtin_amdgcn_mfma_f32_16x16x32_bf16(
                        aF[m][ks], b0[n][ks], acc[m + 2][n], 0, 0, 0);
        __builtin_amdgcn_s_setprio(0);
    }

    const int row0 = rowBase + wm * 64 + ((lane >> 4) << 2);
    const int col0 = colBase + wn * 64 + (lane & 15);
    long long cb = (long long)bz * sC;
    if (EPI == 0) {
#pragma unroll
        for (int m = 0; m < 4; m++)
#pragma unroll
            for (int n = 0; n < 4; n++) {
                f32x4 v = acc[m][n];
#pragma unroll
                for (int j = 0; j < 4; j++) {
                    size_t idx = (size_t)(row0 + m * 16 + j) * ldc + (col0 + n * 16);
                    ((u16*)Cv)[cb + idx] = f2bf(v[j] * scale);
                }
            }
    } else {  // EPI == 3: fp32 out, divide by softmax denominator
        const float* dz = denom + (long long)bz * 2048;
        float inv[4][4];
#pragma unroll
        for (int m = 0; m < 4; m++)
#pragma unroll
            for (int j = 0; j < 4; j++)
                inv[m][j] = 1.0f / dz[row0 + m * 16 + j];
#pragma unroll
        for (int m = 0; m < 4; m++)
#pragma unroll
            for (int n = 0; n < 4; n++) {
                f32x4 v = acc[m][n];
#pragma unroll
                for (int j = 0; j < 4; j++) {
                    size_t idx = (size_t)(row0 + m * 16 + j) * ldc + (col0 + n * 16);
                    ((float*)Cv)[cb + idx] = v[j] * inv[m][j];
                }
            }
    }
}

// ---------------- launch ----------------
extern "C" void kernel_launch(void* const* d_in, const int* in_sizes, int n_in,
                              void* d_out, int out_size, void* d_ws, size_t ws_size,
                              hipStream_t stream) {
    const float* x  = (const float*)d_in[0];
    const float* Wk = (const float*)d_in[1];
    const float* Wq = (const float*)d_in[2];
    const float* Wv = (const float*)d_in[3];
    float* out = (float*)d_out;
    char* ws = (char*)d_ws;
    const size_t MB = 1u << 20;

    u16* xb    = (u16*)(ws);             // 16MB [8192][1024]
    u16* Wqk   = (u16*)(ws + 16 * MB);   // 4MB  [2048][1024]: rows 0-1023 Wq, 1024-2047 Wk
    u16* Wvb   = (u16*)(ws + 20 * MB);   // 2MB
    float* den = (float*)(ws + 24 * MB); // 32KB [4][2048] softmax denominators
    u16* QK    = (u16*)(ws + 64 * MB);   // 32MB [8192][2048]: cols 0-1023 Q, 1024-2047 K
    u16* VT    = (u16*)(ws + 96 * MB);   // 16MB [1024][8192]: VT[o][b*2048+s]
    u16* Pb    = (u16*)(ws + 112 * MB);  // 32MB [4][2048][2048] unnormalized exp(scores)

    const long long SS = 2048LL * 2048;

    hipFuncSetAttribute((const void*)gemm256<0>, hipFuncAttributeMaxDynamicSharedMemorySize, 131072);
    hipFuncSetAttribute((const void*)gemm256<2>, hipFuncAttributeMaxDynamicSharedMemorySize, 131072);
    hipFuncSetAttribute((const void*)gemm256n128<0>, hipFuncAttributeMaxDynamicSharedMemorySize, 98304);
    hipFuncSetAttribute((const void*)gemm256n128<3>, hipFuncAttributeMaxDynamicSharedMemorySize, 98304);

    // fused prologue: x/Wq/Wk/Wv casts + den zero in one dispatch
    prep_kernel<<<2048, 256, 0, stream>>>(x, Wq, Wk, Wv, xb, Wqk, Wvb, den);

    // [Q|K] = x @ [Wq|Wk]^T : M=8192, N=2048, K=1024 (256 blocks)
    gemm256<0><<<dim3(32, 8, 1), 512, 131072, stream>>>(
        xb, Wqk, QK, 1024, 1024, 1024, 2048, 0, 0, 0, 1.0f, nullptr);
    // V^T = Wv @ x^T : M=1024, N=8192, K=1024 (256 blocks)
    gemm256n128<0><<<dim3(4, 64, 1), 512, 98304, stream>>>(
        Wvb, xb, VT, 1024, 1024, 1024, 8192, 0, 0, 0, 1.0f, nullptr);
    // P_unnorm = exp((Q @ K^T)/32), denom += row sums : per batch (256 blocks)
    gemm256<2><<<dim3(8, 8, 4), 512, 131072, stream>>>(
        QK, QK + 1024, Pb, 1024, 2048, 2048, 2048, SS, SS, SS, 0.03125f, den);
    // ctx = (P_unnorm @ (V^T)^T) / denom : per batch (256 blocks)
    gemm256n128<3><<<dim3(8, 8, 4), 512, 98304, stream>>>(
        Pb, VT, out, 2048, 2048, 8192, 1024, SS, 2048LL, 2048LL * 1024, 1.0f, den);
}